// Round 2
// baseline (273.797 us; speedup 1.0000x reference)
//
#include <hip/hip_runtime.h>
#include <stdint.h>

// Problem constants (fixed by the reference setup)
#define B_ 32
#define I_ 16384
#define H_ 1024
#define T_ 10
#define M_ 320   // T_*B_  (GEMM M dimension, m = t*32 + b)
#define MT_ 128  // GEMM per-block M tile (3 tiles cover 320 with padding)

typedef __attribute__((ext_vector_type(8))) short short8;  // 8 bf16 (4 VGPRs)
typedef __attribute__((ext_vector_type(4))) float f32x4;
typedef __attribute__((ext_vector_type(4))) unsigned int u32x4;

// ---------------------------------------------------------------------------
// Kernel 1: pack spikes [B][I][T] f32 -> Sbf [M=T*B][I] bf16 (exact: 0/1)
// 512 blocks, i-chunk of 32 per block; f32x4 global loads, LDS transpose.
// ---------------------------------------------------------------------------
__global__ __launch_bounds__(256) void pack_s(const float* __restrict__ spikes,
                                              uint16_t* __restrict__ Sbf) {
  __shared__ uint16_t tile[M_ * 40];  // [m][il], il<32 padded to 40 (80B rows)
  const int i0 = blockIdx.x * 32;
  // load: 32 b-rows x 320 contiguous floats = 2560 f32x4, 10/thread
#pragma unroll
  for (int p = 0; p < 10; p++) {
    int e = p * 256 + threadIdx.x;          // f32x4 index
    int b = e / 80;                          // 80 f32x4 per b-row
    int r = e - b * 80;
    f32x4 val = *(const f32x4*)&spikes[(size_t)b * (I_ * T_) + (size_t)i0 * T_ + r * 4];
#pragma unroll
    for (int j = 0; j < 4; j++) {
      int pos = r * 4 + j;                   // pos = il*10 + t
      int il = pos / 10;
      int t = pos - il * 10;
      float f = (j == 0) ? val.x : (j == 1) ? val.y : (j == 2) ? val.z : val.w;
      union { float f; unsigned int u; } cv; cv.f = f;
      tile[(t * 32 + b) * 40 + il] = (uint16_t)(cv.u >> 16);  // exact for 0/1
    }
  }
  __syncthreads();
  // store: 320 rows x 32 bf16 = 1280 u32x4, 5/thread
#pragma unroll
  for (int p = 0; p < 5; p++) {
    int e = p * 256 + threadIdx.x;
    int m = e >> 2, il8 = e & 3;
    u32x4 w = *(const u32x4*)&tile[m * 40 + il8 * 8];
    *(u32x4*)&Sbf[(size_t)m * I_ + i0 + il8 * 8] = w;
  }
}

// ---------------------------------------------------------------------------
// Kernel 2: GEMM  partial[ks][320][1024] = Sbf * (weight*strength)
// 2-term bf16 split (w = hi + lo) for fp32-class accuracy.
// Grid = 3 mt x 16 nt x KS  (768 blocks at KS=16 -> 3 blocks/CU).
// Block: 256 thr, tile MT_=128 m x 64 n x kchunk. mt fastest-varying so the 3
// blocks sharing one weight slice are temporally adjacent (LLC locality).
// ---------------------------------------------------------------------------
__global__ __launch_bounds__(256, 3) void gemm(const uint16_t* __restrict__ Sbf,
                                               const float* __restrict__ Wg,
                                               const float* __restrict__ Sg,
                                               float* __restrict__ partial,
                                               int kchunk) {
  // A rows: 32 bf16 padded to 56 (28 words) -> balanced banks, 16B-aligned
  __shared__ uint16_t A_lds[MT_ * 56];
  // W packed hi|lo<<16, [n][k] rows of 36 words; k-blocks XOR-swizzled by
  // (n>>2)&7 so transpose writes are <=2-way bank conflicts
  __shared__ unsigned int W_lds[64 * 36];

  const int bid = blockIdx.x;
  const int mt = bid % 3;
  const int rest = bid / 3;
  const int nt = rest & 15;
  const int ks = rest >> 4;
  const int mbase = mt * MT_;
  const int n0 = nt * 64;
  const int tid = threadIdx.x;
  const int lane = tid & 63, wid = tid >> 6;
  const int quad = lane >> 4, l15 = lane & 15;

  f32x4 acc[2][4];
#pragma unroll
  for (int a = 0; a < 2; a++)
#pragma unroll
    for (int b = 0; b < 4; b++) acc[a][b] = f32x4{0.f, 0.f, 0.f, 0.f};

  unsigned int* A32 = (unsigned int*)A_lds;
  const int stages = kchunk >> 5;       // BK = 32
  const int kofs = ks * kchunk;

  for (int s = 0; s < stages; ++s) {
    const int kbase = kofs + (s << 5);
    __syncthreads();  // previous compute done reading LDS
    // ---- stage A: 128x32 bf16 = 8KB, 2 passes of 16B/thread ----
#pragma unroll
    for (int p = 0; p < 2; p++) {
      int e = p * 256 + tid;
      int m = e >> 2, kq = e & 3;
      int mg = mbase + m;
      u32x4 av = u32x4{0u, 0u, 0u, 0u};
      if (mg < M_) av = *(const u32x4*)&Sbf[(size_t)mg * I_ + kbase + kq * 8];
      *(u32x4*)&A32[m * 28 + kq * 4] = av;
    }
    // ---- stage W: f32x4 reads (n fast, coalesced 1KB/wave), hi/lo split,
    //      transposed scatter into W_lds with XOR k-block swizzle ----
#pragma unroll
    for (int p = 0; p < 2; p++) {
      int e = p * 256 + tid;
      int k = e >> 4;                   // 0..31
      int nq = e & 15;                  // n-quad
      size_t g = (size_t)(kbase + k) * H_ + n0 + nq * 4;
      f32x4 wv = *(const f32x4*)&Wg[g];
      f32x4 sv = *(const f32x4*)&Sg[g];
      float prod[4] = {wv.x * sv.x, wv.y * sv.y, wv.z * sv.z, wv.w * sv.w};
      int pblk = ((k >> 2) ^ (nq & 7)) << 2;
      int koff = pblk + (k & 3);
#pragma unroll
      for (int j = 0; j < 4; j++) {
        union { float f; unsigned int u; } cv; cv.f = prod[j];
        unsigned int hb = (cv.u + 0x7FFFu + ((cv.u >> 16) & 1u)) >> 16;  // RNE
        union { unsigned int u; float f; } hv; hv.u = hb << 16;
        float lo = prod[j] - hv.f;                                 // exact
        union { float f; unsigned int u; } cl; cl.f = lo;
        unsigned int lb = (cl.u + 0x7FFFu + ((cl.u >> 16) & 1u)) >> 16;
        W_lds[(nq * 4 + j) * 36 + koff] = hb | (lb << 16);
      }
    }
    __syncthreads();
    // ---- compute: 2 m-tiles x 4 n-tiles x (hi,lo) = 16 MFMA/wave/stage ----
    short8 af[2];
#pragma unroll
    for (int tm = 0; tm < 2; tm++) {
      int m = wid * 32 + tm * 16 + l15;   // A[m][k]: m=lane&15, k=quad*8+j
      af[tm] = *(const short8*)&A32[m * 28 + quad * 4];
    }
#pragma unroll
    for (int tn = 0; tn < 4; tn++) {
      int n = tn * 16 + l15;              // B[k][n]: n=lane&15, k=quad*8+j
      int gsw = (n >> 2) & 7;
      u32x4 r0 = *(const u32x4*)&W_lds[n * 36 + (((2 * quad) ^ gsw) << 2)];
      u32x4 r1 = *(const u32x4*)&W_lds[n * 36 + (((2 * quad + 1) ^ gsw) << 2)];
      u32x4 hu, lu;
      hu.x = (r0.x & 0xffffu) | (r0.y << 16);
      hu.y = (r0.z & 0xffffu) | (r0.w << 16);
      hu.z = (r1.x & 0xffffu) | (r1.y << 16);
      hu.w = (r1.z & 0xffffu) | (r1.w << 16);
      lu.x = (r0.x >> 16) | (r0.y & 0xffff0000u);
      lu.y = (r0.z >> 16) | (r0.w & 0xffff0000u);
      lu.z = (r1.x >> 16) | (r1.y & 0xffff0000u);
      lu.w = (r1.z >> 16) | (r1.w & 0xffff0000u);
      short8 bhi = __builtin_bit_cast(short8, hu);
      short8 blo = __builtin_bit_cast(short8, lu);
#pragma unroll
      for (int tm = 0; tm < 2; tm++) {
        acc[tm][tn] = __builtin_amdgcn_mfma_f32_16x16x32_bf16(af[tm], bhi,
                                                              acc[tm][tn], 0, 0, 0);
        acc[tm][tn] = __builtin_amdgcn_mfma_f32_16x16x32_bf16(af[tm], blo,
                                                              acc[tm][tn], 0, 0, 0);
      }
    }
  }
  // ---- epilogue: C/D layout col=lane&15, row=quad*4+reg; skip pad rows ----
#pragma unroll
  for (int tm = 0; tm < 2; tm++)
#pragma unroll
    for (int tn = 0; tn < 4; tn++) {
      int mrow = mbase + wid * 32 + tm * 16 + quad * 4;
      if (mrow < M_) {
        int ncol = n0 + tn * 16 + l15;
        float* dst = partial + ((size_t)ks * M_ + mrow) * H_ + ncol;
        dst[0 * H_] = acc[tm][tn].x;
        dst[1 * H_] = acc[tm][tn].y;
        dst[2 * H_] = acc[tm][tn].z;
        dst[3 * H_] = acc[tm][tn].w;
      }
    }
}

// ---------------------------------------------------------------------------
// Kernel 3: deterministic reduction of K-split partials -> weighted [320][1024]
// ---------------------------------------------------------------------------
__global__ __launch_bounds__(256) void reduce_w(const float* __restrict__ partial,
                                                float* __restrict__ weighted,
                                                int KS) {
  int j = (blockIdx.x * 256 + threadIdx.x) * 4;
  f32x4 s = f32x4{0.f, 0.f, 0.f, 0.f};
  for (int k = 0; k < KS; k++) {
    f32x4 p = *(const f32x4*)&partial[(size_t)k * (M_ * H_) + j];
    s += p;
  }
  *(f32x4*)&weighted[j] = s;
}

// ---------------------------------------------------------------------------
// Kernel 4: LIF scan, barrier-free. 16 blocks x 64 thr (1 wave each); thread
// owns one h and ALL 32 batches in registers. Homeostatic threshold update is
// purely per-h -> no cross-thread communication. Diag means via wave shuffle
// + one atomicAdd per wave per step (diag region zeroed by hipMemsetAsync).
// ---------------------------------------------------------------------------
__global__ __launch_bounds__(64) void scan(const float* __restrict__ weighted,
                                           const float* __restrict__ threshold,
                                           const float* __restrict__ fre0,
                                           const float* __restrict__ p_tau_mem,
                                           const float* __restrict__ p_tau_syn,
                                           const float* __restrict__ p_target,
                                           const float* __restrict__ p_lr,
                                           float* __restrict__ out) {
  const int h = blockIdx.x * 64 + threadIdx.x;
  const float alpha_mem = expf(-0.001f / p_tau_mem[0]);
  const float alpha_syn = expf(-0.001f / p_tau_syn[0]);
  const float target = p_target[0], lr = p_lr[0];
  float v[B_], isyn[B_];
#pragma unroll
  for (int b = 0; b < B_; b++) { v[b] = 0.f; isyn[b] = 0.f; }
  float fre = fre0[h];
  float thr = threshold[h];
  for (int t = 0; t < T_; t++) {
    float rsum = 0.f, vsum = 0.f;
#pragma unroll
    for (int b = 0; b < B_; b++) {
      float w_in = weighted[(size_t)(t * 32 + b) * H_ + h];
      isyn[b] = alpha_syn * isyn[b] + w_in;
      v[b] = alpha_mem * v[b] + isyn[b];
      float spike = (v[b] >= thr) ? 1.f : 0.f;
      v[b] -= spike * thr;
      out[(size_t)b * (H_ * T_) + (size_t)h * T_ + t] = spike;
      rsum += spike;
      vsum += v[b];
    }
    float rate = rsum * (1.f / 32.f);
    fre = 0.99f * fre + 0.01f * rate;
    thr = thr + lr * (fre - target);
    // wave-wide sums for diagnostics
    float rr = rate, vv = vsum, tt = thr;
#pragma unroll
    for (int off = 32; off >= 1; off >>= 1) {
      rr += __shfl_xor(rr, off);
      vv += __shfl_xor(vv, off);
      tt += __shfl_xor(tt, off);
    }
    if (threadIdx.x == 0) {
      atomicAdd(&out[327680 + t], vv * (1.f / 32768.f));  // mem mean over B,H
      atomicAdd(&out[327690 + t], rr * (1.f / 1024.f));   // rate mean over H
      atomicAdd(&out[327700 + t], tt * (1.f / 1024.f));   // thr mean over H
    }
  }
}

// ---------------------------------------------------------------------------
extern "C" void kernel_launch(void* const* d_in, const int* in_sizes, int n_in,
                              void* d_out, int out_size, void* d_ws, size_t ws_size,
                              hipStream_t stream) {
  const float* spikes    = (const float*)d_in[0];
  const float* weight    = (const float*)d_in[1];
  const float* strength  = (const float*)d_in[2];
  const float* threshold = (const float*)d_in[3];
  const float* fre0      = (const float*)d_in[4];
  const float* tau_mem   = (const float*)d_in[5];
  const float* tau_syn   = (const float*)d_in[6];
  const float* target    = (const float*)d_in[7];
  const float* lr        = (const float*)d_in[8];
  float* out = (float*)d_out;

  const size_t sbf_bytes = (size_t)M_ * I_ * 2;   // 10.5 MB bf16 A-matrix
  const size_t slice     = (size_t)M_ * H_ * 4;   // 1.31 MB per K-split partial
  int KS = 16;                                    // shrink if ws is small
  while (KS > 1 && sbf_bytes + (size_t)(KS + 1) * slice > ws_size) KS >>= 1;

  uint16_t* Sbf   = (uint16_t*)d_ws;
  float* partial  = (float*)((char*)d_ws + sbf_bytes);
  float* weighted = (float*)((char*)d_ws + sbf_bytes + (size_t)KS * slice);

  pack_s<<<I_ / 32, 256, 0, stream>>>(spikes, Sbf);
  gemm<<<3 * 16 * KS, 256, 0, stream>>>(Sbf, weight, strength, partial, I_ / KS);
  reduce_w<<<(M_ * H_) / 1024, 256, 0, stream>>>(partial, weighted, KS);
  hipMemsetAsync(out + 327680, 0, 30 * sizeof(float), stream);
  scan<<<H_ / 64, 64, 0, stream>>>(weighted, threshold, fre0, tau_mem, tau_syn,
                                   target, lr, out);
}

// Round 3
// 269.234 us; speedup vs baseline: 1.0169x; 1.0169x over previous
//
#include <hip/hip_runtime.h>
#include <stdint.h>

// Problem constants (fixed by the reference setup)
#define B_ 32
#define I_ 16384
#define H_ 1024
#define T_ 10
#define M_ 320   // T_*B_  (GEMM M dimension, m = t*32 + b)
#define NW 32    // GEMM per-block n-tile width

typedef __attribute__((ext_vector_type(8))) short short8;  // 8 bf16 (4 VGPRs)
typedef __attribute__((ext_vector_type(4))) float f32x4;
typedef __attribute__((ext_vector_type(2))) float f32x2;
typedef __attribute__((ext_vector_type(4))) unsigned int u32x4;

// ---------------------------------------------------------------------------
// Kernel 1: pack spikes [B][I][T] f32 -> Sbf [M=T*B][I] bf16 (exact: 0/1)
// 512 blocks, i-chunk of 32 per block; f32x4 global loads, LDS transpose.
// ---------------------------------------------------------------------------
__global__ __launch_bounds__(256) void pack_s(const float* __restrict__ spikes,
                                              uint16_t* __restrict__ Sbf) {
  __shared__ __align__(16) uint16_t tile[M_ * 40];  // [m][il], il<32 pad->40
  const int i0 = blockIdx.x * 32;
#pragma unroll
  for (int p = 0; p < 10; p++) {
    int e = p * 256 + threadIdx.x;          // f32x4 index
    int b = e / 80;                          // 80 f32x4 per b-row
    int r = e - b * 80;
    f32x4 val = *(const f32x4*)&spikes[(size_t)b * (I_ * T_) + (size_t)i0 * T_ + r * 4];
#pragma unroll
    for (int j = 0; j < 4; j++) {
      int pos = r * 4 + j;                   // pos = il*10 + t
      int il = pos / 10;
      int t = pos - il * 10;
      float f = (j == 0) ? val.x : (j == 1) ? val.y : (j == 2) ? val.z : val.w;
      union { float f; unsigned int u; } cv; cv.f = f;
      tile[(t * 32 + b) * 40 + il] = (uint16_t)(cv.u >> 16);  // exact for 0/1
    }
  }
  __syncthreads();
#pragma unroll
  for (int p = 0; p < 5; p++) {
    int e = p * 256 + threadIdx.x;
    int m = e >> 2, il8 = e & 3;
    u32x4 w = *(const u32x4*)&tile[m * 40 + il8 * 8];
    *(u32x4*)&Sbf[(size_t)m * I_ + i0 + il8 * 8] = w;
  }
}

// ---------------------------------------------------------------------------
// Kernel 2: GEMM  partial[ks][320][1024] = Sbf * (weight*strength)
// 2-term bf16 split (w = hi + lo) for fp32-class accuracy.
// Block = 640 thr (10 waves) x FULL M=320 x NW=32 n x kchunk. Weight and
// strength are read EXACTLY ONCE from HBM (no M-split! R2's M-split caused
// 2.2x weight re-fetch). Grid = 32 nt x KS -> 512 blocks = 2 blocks/CU,
// 20 waves/CU. hi/lo stored as separate bf16 LDS planes -> B-frags are
// straight ds_read_b128, no per-stage unpack VALU.
// Wave w owns m-rows [32w, 32w+32): 2 m-tiles x 2 n-tiles x {hi,lo} = 8 MFMA.
// ---------------------------------------------------------------------------
__global__ __launch_bounds__(640, 5) void gemm(const uint16_t* __restrict__ Sbf,
                                               const float* __restrict__ Wg,
                                               const float* __restrict__ Sg,
                                               float* __restrict__ partial,
                                               int kchunk) {
  // all rows padded 32 bf16 -> 40 (80B): 16B-aligned b128, 2-way banks (free)
  __shared__ __align__(16) uint16_t A_lds[M_ * 40];  // 25.6 KB
  __shared__ __align__(16) uint16_t Whi[NW * 40];    // 2.56 KB
  __shared__ __align__(16) uint16_t Wlo[NW * 40];    // 2.56 KB

  const int nt = blockIdx.x & 31;      // nt fastest: blocks sharing Sbf slice
  const int ks = blockIdx.x >> 5;      // are temporally adjacent (LLC)
  const int nbase = nt * NW;
  const int tid = threadIdx.x;
  const int lane = tid & 63, wid = tid >> 6;   // wid 0..9
  const int quad = lane >> 4, l15 = lane & 15;

  f32x4 acc[2][2];
#pragma unroll
  for (int a = 0; a < 2; a++)
#pragma unroll
    for (int b = 0; b < 2; b++) acc[a][b] = f32x4{0.f, 0.f, 0.f, 0.f};

  const int stages = kchunk >> 5;      // BK = 32
  const int kofs = ks * kchunk;
  // W staging mapping (tid < 256): thread owns k-pair x n-pair
  const int kp = (tid >> 4) & 15;      // k-pair index 0..15
  const int np = tid & 15;             // n-pair index 0..15

  for (int s = 0; s < stages; ++s) {
    const int kbase = kofs + (s << 5);
    __syncthreads();  // previous compute done reading LDS
    // ---- stage A: 320x32 bf16 = 20KB, 2 passes of 16B/thread ----
#pragma unroll
    for (int p = 0; p < 2; p++) {
      int e = p * 640 + tid;
      int m = e >> 2, kq = e & 3;
      u32x4 av = *(const u32x4*)&Sbf[(size_t)m * I_ + kbase + kq * 8];
      *(u32x4*)&A_lds[m * 40 + kq * 8] = av;
    }
    // ---- stage W (waves 0..3): 32k x 32n, f32x2 row-pairs, hi/lo split ----
    if (tid < 256) {
      size_t g0 = (size_t)(kbase + 2 * kp) * H_ + nbase + 2 * np;
      f32x2 w0 = *(const f32x2*)&Wg[g0];
      f32x2 w1 = *(const f32x2*)&Wg[g0 + H_];
      f32x2 s0 = *(const f32x2*)&Sg[g0];
      f32x2 s1 = *(const f32x2*)&Sg[g0 + H_];
      float pr[2][2] = {{w0.x * s0.x, w1.x * s1.x},    // [nn][kk]
                        {w0.y * s0.y, w1.y * s1.y}};
      unsigned int hb[2][2], lb[2][2];
#pragma unroll
      for (int nn = 0; nn < 2; nn++)
#pragma unroll
        for (int kk = 0; kk < 2; kk++) {
          union { float f; unsigned int u; } cv; cv.f = pr[nn][kk];
          unsigned int h = (cv.u + 0x7FFFu + ((cv.u >> 16) & 1u)) >> 16; // RNE
          union { unsigned int u; float f; } hv; hv.u = h << 16;
          float lo = pr[nn][kk] - hv.f;                            // exact
          union { float f; unsigned int u; } cl; cl.f = lo;
          unsigned int l = (cl.u + 0x7FFFu + ((cl.u >> 16) & 1u)) >> 16;
          hb[nn][kk] = h; lb[nn][kk] = l;
        }
#pragma unroll
      for (int nn = 0; nn < 2; nn++) {
        int n = 2 * np + nn;
        *(unsigned int*)&Whi[n * 40 + 2 * kp] = hb[nn][0] | (hb[nn][1] << 16);
        *(unsigned int*)&Wlo[n * 40 + 2 * kp] = lb[nn][0] | (lb[nn][1] << 16);
      }
    }
    __syncthreads();
    // ---- compute: straight b128 frag reads, 8 MFMA/wave/stage ----
    short8 af[2];
#pragma unroll
    for (int tm = 0; tm < 2; tm++) {
      int m = wid * 32 + tm * 16 + l15;     // A[m][k]: m=lane&15, k=quad*8+j
      af[tm] = *(const short8*)&A_lds[m * 40 + quad * 8];
    }
#pragma unroll
    for (int tn = 0; tn < 2; tn++) {
      int n = tn * 16 + l15;                // B[k][n]: n=lane&15, k=quad*8+j
      short8 bhi = *(const short8*)&Whi[n * 40 + quad * 8];
      short8 blo = *(const short8*)&Wlo[n * 40 + quad * 8];
#pragma unroll
      for (int tm = 0; tm < 2; tm++) {
        acc[tm][tn] = __builtin_amdgcn_mfma_f32_16x16x32_bf16(af[tm], bhi,
                                                              acc[tm][tn], 0, 0, 0);
        acc[tm][tn] = __builtin_amdgcn_mfma_f32_16x16x32_bf16(af[tm], blo,
                                                              acc[tm][tn], 0, 0, 0);
      }
    }
  }
  // ---- epilogue: C/D layout col=lane&15, row=quad*4+reg ----
#pragma unroll
  for (int tm = 0; tm < 2; tm++)
#pragma unroll
    for (int tn = 0; tn < 2; tn++) {
      int mrow = wid * 32 + tm * 16 + quad * 4;
      int ncol = nbase + tn * 16 + l15;
      float* dst = partial + ((size_t)ks * M_ + mrow) * H_ + ncol;
      dst[0 * H_] = acc[tm][tn].x;
      dst[1 * H_] = acc[tm][tn].y;
      dst[2 * H_] = acc[tm][tn].z;
      dst[3 * H_] = acc[tm][tn].w;
    }
}

// ---------------------------------------------------------------------------
// Kernel 3: deterministic reduction of K-split partials -> weighted [320][1024]
// Also zeroes the diag region of out (replaces a memset dispatch; scan runs
// after us on the same stream).
// ---------------------------------------------------------------------------
__global__ __launch_bounds__(256) void reduce_w(const float* __restrict__ partial,
                                                float* __restrict__ weighted,
                                                float* __restrict__ out, int KS) {
  if (blockIdx.x == 0 && threadIdx.x < 30) out[327680 + threadIdx.x] = 0.f;
  int j = (blockIdx.x * 256 + threadIdx.x) * 4;
  f32x4 s = f32x4{0.f, 0.f, 0.f, 0.f};
  for (int k = 0; k < KS; k++) {
    f32x4 p = *(const f32x4*)&partial[(size_t)k * (M_ * H_) + j];
    s += p;
  }
  *(f32x4*)&weighted[j] = s;
}

// ---------------------------------------------------------------------------
// Kernel 4: LIF scan, barrier-free. 16 blocks x 64 thr (1 wave each); thread
// owns one h and ALL 32 batches in registers. Threshold update is per-h ->
// no cross-thread communication. Diag means via wave shuffle + one atomicAdd
// per wave per step (diag region zeroed by reduce_w).
// ---------------------------------------------------------------------------
__global__ __launch_bounds__(64) void scan(const float* __restrict__ weighted,
                                           const float* __restrict__ threshold,
                                           const float* __restrict__ fre0,
                                           const float* __restrict__ p_tau_mem,
                                           const float* __restrict__ p_tau_syn,
                                           const float* __restrict__ p_target,
                                           const float* __restrict__ p_lr,
                                           float* __restrict__ out) {
  const int h = blockIdx.x * 64 + threadIdx.x;
  const float alpha_mem = expf(-0.001f / p_tau_mem[0]);
  const float alpha_syn = expf(-0.001f / p_tau_syn[0]);
  const float target = p_target[0], lr = p_lr[0];
  float v[B_], isyn[B_];
#pragma unroll
  for (int b = 0; b < B_; b++) { v[b] = 0.f; isyn[b] = 0.f; }
  float fre = fre0[h];
  float thr = threshold[h];
  for (int t = 0; t < T_; t++) {
    float rsum = 0.f, vsum = 0.f;
#pragma unroll
    for (int b = 0; b < B_; b++) {
      float w_in = weighted[(size_t)(t * 32 + b) * H_ + h];
      isyn[b] = alpha_syn * isyn[b] + w_in;
      v[b] = alpha_mem * v[b] + isyn[b];
      float spike = (v[b] >= thr) ? 1.f : 0.f;
      v[b] -= spike * thr;
      out[(size_t)b * (H_ * T_) + (size_t)h * T_ + t] = spike;
      rsum += spike;
      vsum += v[b];
    }
    float rate = rsum * (1.f / 32.f);
    fre = 0.99f * fre + 0.01f * rate;
    thr = thr + lr * (fre - target);
    float rr = rate, vv = vsum, tt = thr;
#pragma unroll
    for (int off = 32; off >= 1; off >>= 1) {
      rr += __shfl_xor(rr, off);
      vv += __shfl_xor(vv, off);
      tt += __shfl_xor(tt, off);
    }
    if (threadIdx.x == 0) {
      atomicAdd(&out[327680 + t], vv * (1.f / 32768.f));  // mem mean over B,H
      atomicAdd(&out[327690 + t], rr * (1.f / 1024.f));   // rate mean over H
      atomicAdd(&out[327700 + t], tt * (1.f / 1024.f));   // thr mean over H
    }
  }
}

// ---------------------------------------------------------------------------
extern "C" void kernel_launch(void* const* d_in, const int* in_sizes, int n_in,
                              void* d_out, int out_size, void* d_ws, size_t ws_size,
                              hipStream_t stream) {
  const float* spikes    = (const float*)d_in[0];
  const float* weight    = (const float*)d_in[1];
  const float* strength  = (const float*)d_in[2];
  const float* threshold = (const float*)d_in[3];
  const float* fre0      = (const float*)d_in[4];
  const float* tau_mem   = (const float*)d_in[5];
  const float* tau_syn   = (const float*)d_in[6];
  const float* target    = (const float*)d_in[7];
  const float* lr        = (const float*)d_in[8];
  float* out = (float*)d_out;

  const size_t sbf_bytes = (size_t)M_ * I_ * 2;   // 10.5 MB bf16 A-matrix
  const size_t slice     = (size_t)M_ * H_ * 4;   // 1.31 MB per K-split partial
  int KS = 16;                                    // shrink if ws is small
  while (KS > 1 && sbf_bytes + (size_t)(KS + 1) * slice > ws_size) KS >>= 1;

  uint16_t* Sbf   = (uint16_t*)d_ws;
  float* partial  = (float*)((char*)d_ws + sbf_bytes);
  float* weighted = (float*)((char*)d_ws + sbf_bytes + (size_t)KS * slice);

  pack_s<<<I_ / 32, 256, 0, stream>>>(spikes, Sbf);
  gemm<<<32 * KS, 640, 0, stream>>>(Sbf, weight, strength, partial, I_ / KS);
  reduce_w<<<(M_ * H_) / 1024, 256, 0, stream>>>(partial, weighted, out, KS);
  scan<<<H_ / 64, 64, 0, stream>>>(weighted, threshold, fre0, tau_mem, tau_syn,
                                   target, lr, out);
}

// Round 4
// 239.929 us; speedup vs baseline: 1.1412x; 1.1221x over previous
//
#include <hip/hip_runtime.h>
#include <stdint.h>

// Problem constants (fixed by the reference setup)
#define B_ 32
#define I_ 16384
#define H_ 1024
#define T_ 10
#define M_ 320   // T_*B_  (GEMM M dimension, m = t*32 + b)
#define NW 32    // GEMM per-block n-tile width

typedef __attribute__((ext_vector_type(8))) short short8;  // 8 bf16 (4 VGPRs)
typedef __attribute__((ext_vector_type(4))) float f32x4;
typedef __attribute__((ext_vector_type(4))) unsigned int u32x4;

// ---------------------------------------------------------------------------
// Kernel 1: pack spikes [B][I][T] f32 -> Sbf [M=T*B][I] bf16 (exact: 0/1)
// ---------------------------------------------------------------------------
__global__ __launch_bounds__(256) void pack_s(const float* __restrict__ spikes,
                                              uint16_t* __restrict__ Sbf) {
  __shared__ __align__(16) uint16_t tile[M_ * 40];  // [m][il], il<32 pad->40
  const int i0 = blockIdx.x * 32;
#pragma unroll
  for (int p = 0; p < 10; p++) {
    int e = p * 256 + threadIdx.x;          // f32x4 index
    int b = e / 80;                          // 80 f32x4 per b-row
    int r = e - b * 80;
    f32x4 val = *(const f32x4*)&spikes[(size_t)b * (I_ * T_) + (size_t)i0 * T_ + r * 4];
#pragma unroll
    for (int j = 0; j < 4; j++) {
      int pos = r * 4 + j;                   // pos = il*10 + t
      int il = pos / 10;
      int t = pos - il * 10;
      float f = (j == 0) ? val.x : (j == 1) ? val.y : (j == 2) ? val.z : val.w;
      union { float f; unsigned int u; } cv; cv.f = f;
      tile[(t * 32 + b) * 40 + il] = (uint16_t)(cv.u >> 16);  // exact for 0/1
    }
  }
  __syncthreads();
#pragma unroll
  for (int p = 0; p < 5; p++) {
    int e = p * 256 + threadIdx.x;
    int m = e >> 2, il8 = e & 3;
    u32x4 w = *(const u32x4*)&tile[m * 40 + il8 * 8];
    *(u32x4*)&Sbf[(size_t)m * I_ + i0 + il8 * 8] = w;
  }
}

// ---------------------------------------------------------------------------
// Kernel 2: GEMM  partial[ks][320][1024] = Sbf * (weight*strength)
// 2-term bf16 split (w = hi + lo); fp32-class accuracy.
// Block = 640 thr x full M=320 x NW=32 x kchunk; weight read exactly once.
// Software pipeline: A-fragments load GLOBAL->REG directly (the wave-row
// mapping IS the MFMA A layout - no LDS for A at all); W staged through
// double-buffered LDS with 1-stage register prefetch; ONE barrier per stage.
// W LDS rows = 40 ushorts: both write phase (16 lanes, n=l15, fixed ko) and
// read phase (16 lanes, n=l15, fixed quad) give starts 20*l15 mod 32 =
// 8 distinct 4-word offsets x2 -> all 32 banks x2 = conflict-free.
// ---------------------------------------------------------------------------
__global__ __launch_bounds__(640, 5) void gemm(const uint16_t* __restrict__ Sbf,
                                               const float* __restrict__ Wg,
                                               const float* __restrict__ Sg,
                                               float* __restrict__ partial,
                                               int kchunk) {
  __shared__ __align__(16) uint16_t WhiL[2][NW * 40];  // 2.56 KB each
  __shared__ __align__(16) uint16_t WloL[2][NW * 40];

  const int nt = blockIdx.x & 31;      // nt fastest: same-ks blocks adjacent
  const int ks = blockIdx.x >> 5;
  const int nbase = nt * NW;
  const int tid = threadIdx.x;
  const int lane = tid & 63, wid = tid >> 6;   // wid 0..9
  const int quad = lane >> 4, l15 = lane & 15;

  const int stages = kchunk >> 5;      // BK = 32 (stages always even here)
  const int kofs = ks * kchunk;

  // A-fragment pointers: lane holds A[m][quad*8 + j] -> 16B contiguous global
  const uint16_t* aptr0 = Sbf + (size_t)(wid * 32 + l15) * I_ + quad * 8;
  const uint16_t* aptr1 = aptr0 + (size_t)16 * I_;

  // W staging mapping (tid < 128): n-column x k-octet
  const int wn = tid & 31;
  const int wko = (tid >> 5) & 3;

  f32x4 acc[2][2];
#pragma unroll
  for (int a = 0; a < 2; a++)
#pragma unroll
    for (int b = 0; b < 2; b++) acc[a][b] = f32x4{0.f, 0.f, 0.f, 0.f};

  u32x4 afA[2], afB[2];
  float wpre[8], spre[8];

  // pack wpre/spre -> hi/lo planes of LDS buffer pn
#define PACK_W(pn)                                                          \
  if (tid < 128) {                                                          \
    unsigned int hw[4], lw[4];                                              \
    _Pragma("unroll")                                                       \
    for (int j2 = 0; j2 < 4; j2++) {                                        \
      unsigned int hh[2], ll[2];                                            \
      _Pragma("unroll")                                                     \
      for (int e = 0; e < 2; e++) {                                         \
        float p = wpre[j2 * 2 + e] * spre[j2 * 2 + e];                      \
        union { float f; unsigned int u; } cv; cv.f = p;                    \
        unsigned int hb = (cv.u + 0x7FFFu + ((cv.u >> 16) & 1u)) >> 16;     \
        union { unsigned int u; float f; } hv; hv.u = hb << 16;             \
        float lo = p - hv.f;                                                \
        union { float f; unsigned int u; } cl; cl.f = lo;                   \
        unsigned int lb = (cl.u + 0x7FFFu + ((cl.u >> 16) & 1u)) >> 16;     \
        hh[e] = hb; ll[e] = lb;                                             \
      }                                                                     \
      hw[j2] = hh[0] | (hh[1] << 16);                                       \
      lw[j2] = ll[0] | (ll[1] << 16);                                       \
    }                                                                       \
    *(u32x4*)&WhiL[pn][wn * 40 + wko * 8] = u32x4{hw[0], hw[1], hw[2], hw[3]}; \
    *(u32x4*)&WloL[pn][wn * 40 + wko * 8] = u32x4{lw[0], lw[1], lw[2], lw[3]}; \
  }

#define LOAD_W(kb)                                                          \
  if (tid < 128) {                                                          \
    _Pragma("unroll")                                                       \
    for (int j = 0; j < 8; j++) {                                           \
      size_t g = (size_t)((kb) + wko * 8 + j) * H_ + nbase + wn;            \
      wpre[j] = Wg[g]; spre[j] = Sg[g];                                     \
    }                                                                       \
  }

#define COMPUTE(AF, pc)                                                     \
  {                                                                         \
    short8 a0 = __builtin_bit_cast(short8, AF[0]);                          \
    short8 a1 = __builtin_bit_cast(short8, AF[1]);                          \
    _Pragma("unroll")                                                       \
    for (int tn = 0; tn < 2; tn++) {                                        \
      int n = tn * 16 + l15;                                                \
      short8 bhi = *(const short8*)&WhiL[pc][n * 40 + quad * 8];            \
      short8 blo = *(const short8*)&WloL[pc][n * 40 + quad * 8];            \
      acc[0][tn] = __builtin_amdgcn_mfma_f32_16x16x32_bf16(a0, bhi, acc[0][tn], 0, 0, 0); \
      acc[0][tn] = __builtin_amdgcn_mfma_f32_16x16x32_bf16(a0, blo, acc[0][tn], 0, 0, 0); \
      acc[1][tn] = __builtin_amdgcn_mfma_f32_16x16x32_bf16(a1, bhi, acc[1][tn], 0, 0, 0); \
      acc[1][tn] = __builtin_amdgcn_mfma_f32_16x16x32_bf16(a1, blo, acc[1][tn], 0, 0, 0); \
    }                                                                       \
  }

  // ---- preamble: load+stage 0, prefetch 1 ----
  afA[0] = *(const u32x4*)(aptr0 + kofs);
  afA[1] = *(const u32x4*)(aptr1 + kofs);
  LOAD_W(kofs);
  PACK_W(0);                 // waits wpre(0), writes buf0
  {
    int s1 = (1 < stages) ? 1 : 0;
    int k1 = kofs + (s1 << 5);
    afB[0] = *(const u32x4*)(aptr0 + k1);
    afB[1] = *(const u32x4*)(aptr1 + k1);
    LOAD_W(k1);              // issue only; waited at next PACK_W
  }
  __syncthreads();

  // ---- main loop, unrolled x2 (stages even) ----
  for (int s = 0; s < stages; s += 2) {
    // stage s (even): compute buf0/afA; stage s+1 data -> buf1
    COMPUTE(afA, 0);
    PACK_W(1);
    {
      int s2 = s + 2; if (s2 >= stages) s2 = stages - 1;
      int k2 = kofs + (s2 << 5);
      afA[0] = *(const u32x4*)(aptr0 + k2);
      afA[1] = *(const u32x4*)(aptr1 + k2);
      LOAD_W(k2);
    }
    __syncthreads();
    // stage s+1 (odd): compute buf1/afB; stage s+2 data -> buf0
    COMPUTE(afB, 1);
    PACK_W(0);
    {
      int s3 = s + 3; if (s3 >= stages) s3 = stages - 1;
      int k3 = kofs + (s3 << 5);
      afB[0] = *(const u32x4*)(aptr0 + k3);
      afB[1] = *(const u32x4*)(aptr1 + k3);
      LOAD_W(k3);
    }
    __syncthreads();
  }

  // ---- epilogue: C/D layout col=lane&15, row=quad*4+reg ----
#pragma unroll
  for (int tm = 0; tm < 2; tm++)
#pragma unroll
    for (int tn = 0; tn < 2; tn++) {
      int mrow = wid * 32 + tm * 16 + quad * 4;
      int ncol = nbase + tn * 16 + l15;
      float* dst = partial + ((size_t)ks * M_ + mrow) * H_ + ncol;
      dst[0 * H_] = acc[tm][tn].x;
      dst[1 * H_] = acc[tm][tn].y;
      dst[2 * H_] = acc[tm][tn].z;
      dst[3 * H_] = acc[tm][tn].w;
    }
#undef PACK_W
#undef LOAD_W
#undef COMPUTE
}

// ---------------------------------------------------------------------------
// Kernel 3: deterministic reduction of K-split partials -> weighted [320][1024]
// Also zeroes the diag region of out (scan runs after us on the stream).
// ---------------------------------------------------------------------------
__global__ __launch_bounds__(256) void reduce_w(const float* __restrict__ partial,
                                                float* __restrict__ weighted,
                                                float* __restrict__ out, int KS) {
  if (blockIdx.x == 0 && threadIdx.x < 30) out[327680 + threadIdx.x] = 0.f;
  int j = (blockIdx.x * 256 + threadIdx.x) * 4;
  f32x4 s = f32x4{0.f, 0.f, 0.f, 0.f};
  for (int k = 0; k < KS; k++) {
    f32x4 p = *(const f32x4*)&partial[(size_t)k * (M_ * H_) + j];
    s += p;
  }
  *(f32x4*)&weighted[j] = s;
}

// ---------------------------------------------------------------------------
// Kernel 4: LIF scan, barrier-free. 64 blocks x 64 thr; lane = (bg,hl):
// thread owns h = blk*16+hl and 8 batches (b = bg*8+j). Cross-bg spike-rate
// reduction via in-wave shfl_xor(16/32); threshold update computed
// identically (deterministically) in the 4 lanes sharing an h.
// ---------------------------------------------------------------------------
__global__ __launch_bounds__(64) void scan(const float* __restrict__ weighted,
                                           const float* __restrict__ threshold,
                                           const float* __restrict__ fre0,
                                           const float* __restrict__ p_tau_mem,
                                           const float* __restrict__ p_tau_syn,
                                           const float* __restrict__ p_target,
                                           const float* __restrict__ p_lr,
                                           float* __restrict__ out) {
  const int lane = threadIdx.x;
  const int hl = lane & 15, bg = lane >> 4;
  const int h = blockIdx.x * 16 + hl;
  const float alpha_mem = expf(-0.001f / p_tau_mem[0]);
  const float alpha_syn = expf(-0.001f / p_tau_syn[0]);
  const float target = p_target[0], lr = p_lr[0];
  float v[8], isyn[8];
#pragma unroll
  for (int j = 0; j < 8; j++) { v[j] = 0.f; isyn[j] = 0.f; }
  float fre = fre0[h];
  float thr = threshold[h];
  for (int t = 0; t < T_; t++) {
    float rsum = 0.f, vsum = 0.f;
#pragma unroll
    for (int j = 0; j < 8; j++) {
      int b = bg * 8 + j;
      float w_in = weighted[(size_t)(t * 32 + b) * H_ + h];
      isyn[j] = alpha_syn * isyn[j] + w_in;
      v[j] = alpha_mem * v[j] + isyn[j];
      float spike = (v[j] >= thr) ? 1.f : 0.f;
      v[j] -= spike * thr;
      out[(size_t)b * (H_ * T_) + (size_t)h * T_ + t] = spike;
      rsum += spike;
      vsum += v[j];
    }
    // sum over the 4 bg-lanes of this h (lanes l, l^16, l^32, l^48)
    float r = rsum;
    r += __shfl_xor(r, 16);
    r += __shfl_xor(r, 32);
    float rate = r * (1.f / 32.f);
    fre = 0.99f * fre + 0.01f * rate;               // identical in 4 lanes
    thr = thr + lr * (fre - target);
    // diagnostics: full-wave sums
    float vv = vsum, rr = rate, tt = thr;
#pragma unroll
    for (int off = 32; off >= 1; off >>= 1) {
      vv += __shfl_xor(vv, off);
      rr += __shfl_xor(rr, off);   // = 4 * sum_h rate
      tt += __shfl_xor(tt, off);   // = 4 * sum_h thr
    }
    if (lane == 0) {
      atomicAdd(&out[327680 + t], vv * (1.f / 32768.f));
      atomicAdd(&out[327690 + t], rr * (1.f / 4096.f));   // /(4*1024)
      atomicAdd(&out[327700 + t], tt * (1.f / 4096.f));
    }
  }
}

// ---------------------------------------------------------------------------
extern "C" void kernel_launch(void* const* d_in, const int* in_sizes, int n_in,
                              void* d_out, int out_size, void* d_ws, size_t ws_size,
                              hipStream_t stream) {
  const float* spikes    = (const float*)d_in[0];
  const float* weight    = (const float*)d_in[1];
  const float* strength  = (const float*)d_in[2];
  const float* threshold = (const float*)d_in[3];
  const float* fre0      = (const float*)d_in[4];
  const float* tau_mem   = (const float*)d_in[5];
  const float* tau_syn   = (const float*)d_in[6];
  const float* target    = (const float*)d_in[7];
  const float* lr        = (const float*)d_in[8];
  float* out = (float*)d_out;

  const size_t sbf_bytes = (size_t)M_ * I_ * 2;   // 10.5 MB bf16 A-matrix
  const size_t slice     = (size_t)M_ * H_ * 4;   // 1.31 MB per K-split partial
  int KS = 16;                                    // shrink if ws is small
  while (KS > 1 && sbf_bytes + (size_t)(KS + 1) * slice > ws_size) KS >>= 1;

  uint16_t* Sbf   = (uint16_t*)d_ws;
  float* partial  = (float*)((char*)d_ws + sbf_bytes);
  float* weighted = (float*)((char*)d_ws + sbf_bytes + (size_t)KS * slice);

  pack_s<<<I_ / 32, 256, 0, stream>>>(spikes, Sbf);
  gemm<<<32 * KS, 640, 0, stream>>>(Sbf, weight, strength, partial, I_ / KS);
  reduce_w<<<(M_ * H_) / 1024, 256, 0, stream>>>(partial, weighted, out, KS);
  scan<<<H_ / 16, 64, 0, stream>>>(weighted, threshold, fre0, tau_mem, tau_syn,
                                   target, lr, out);
}